// Round 6
// baseline (375.373 us; speedup 1.0000x reference)
//
#include <hip/hip_runtime.h>

// Collapse: out = P3@(M.T)^3 + 16c@(M.T)^2 + 4c@M.T + c
// Re-associated: out = Y1 @ (M^2).T + u
//   M  = Wzf @ Wsum (Wsum = sum_k Wz[k], fused into B staging, MODE 1)
//   c  = 4*((sum_k bz[k]) @ Wzf.T + bzf)
//   Y1 = P3 @ M.T + 16c ;  u = 4c @ M.T + c ;  P3[t] = sum of tree t's 64 leaves
// Plain dispatches (cooperative launch breaks harness graph capture — R5):
//   D1 (1344 blk): [0,64) M | [64,1088) pool | [1088,1344) c0
//   D2 (448 blk):  [0,128) Y1 | [128,192) M2 | [192,448) u
//   D3 (128 blk):  out
// All blocks 128 threads. GEMM: 64x64 tile, 8x4 microtile (1.5 B/FMA-lane vs
// 2.0 at 4x4 — LDS pipe ~85 B/cyc/CU is the wall), KT=32 dbuf, 1 barrier/tile.

#define HD 512
#define LDT 68   // LDS row stride (floats): 16B-aligned, <=2-way banks (free)

struct GemmSmem {
    float As[2][32][LDT];   // 17408 B
    float Bs[2][32][LDT];   // 17408 B -> 34816 B total, 4 blocks/CU possible
};

// ---- tiled SGEMM: C[i0:+64, j0:+64] = A @ op(B) + bscale*bias ----
// MODE 0: NN   MODE 1: NN with B = sum of 4 Wz slices   MODE 2: NT
// 128 threads: row group rg=tid>>4 (8 rows each), col group cg=tid&15 (4 cols).
template<int MODE>
__device__ __forceinline__
void gemm_tile(const float* __restrict__ A, const float* __restrict__ B,
               float* __restrict__ C, const float* __restrict__ bias,
               float bscale, int i0, int j0, GemmSmem& sm) {
    const int tid  = threadIdx.x;          // 0..127
    const int cg   = tid & 15, rg = tid >> 4;
    const int srow = tid >> 1, skq = (tid & 1) << 2;   // A / NT-B staging
    const int bsk  = tid >> 4, bsc4 = (tid & 15) << 2; // NN-B staging

    float4 ap[4], bp[4];

    auto load_tiles = [&](int k0) {
        const float* ar = &A[(size_t)(i0 + srow) * HD + k0 + skq];
        #pragma unroll
        for (int p = 0; p < 4; ++p) ap[p] = *(const float4*)(ar + 8 * p);
        if (MODE == 2) {
            const float* br = &B[(size_t)(j0 + srow) * HD + k0 + skq];
            #pragma unroll
            for (int p = 0; p < 4; ++p) bp[p] = *(const float4*)(br + 8 * p);
        } else if (MODE == 0) {
            const float* br = &B[(size_t)(k0 + bsk) * HD + j0 + bsc4];
            #pragma unroll
            for (int p = 0; p < 4; ++p) bp[p] = *(const float4*)(br + 8 * p * HD);
        } else {
            const float* br = &B[(size_t)(k0 + bsk) * HD + j0 + bsc4];
            #pragma unroll
            for (int p = 0; p < 4; ++p) {
                const float* b0 = br + 8 * p * HD;
                float4 s = *(const float4*)b0;
                #pragma unroll
                for (int q = 1; q < 4; ++q) {
                    float4 t = *(const float4*)(b0 + q * 262144);
                    s.x += t.x; s.y += t.y; s.z += t.z; s.w += t.w;
                }
                bp[p] = s;
            }
        }
    };
    // Scatter banks: addr=(k)*68+srow -> bank (4k+srow)&31; per wave srow 0..31
    // twice with k offset 0/4 -> every bank hit exactly 2x: free.
    auto store_tiles = [&](int buf) {
        #pragma unroll
        for (int p = 0; p < 4; ++p) {
            sm.As[buf][skq + 8 * p + 0][srow] = ap[p].x;
            sm.As[buf][skq + 8 * p + 1][srow] = ap[p].y;
            sm.As[buf][skq + 8 * p + 2][srow] = ap[p].z;
            sm.As[buf][skq + 8 * p + 3][srow] = ap[p].w;
        }
        if (MODE == 2) {
            #pragma unroll
            for (int p = 0; p < 4; ++p) {
                sm.Bs[buf][skq + 8 * p + 0][srow] = bp[p].x;
                sm.Bs[buf][skq + 8 * p + 1][srow] = bp[p].y;
                sm.Bs[buf][skq + 8 * p + 2][srow] = bp[p].z;
                sm.Bs[buf][skq + 8 * p + 3][srow] = bp[p].w;
            }
        } else {
            #pragma unroll
            for (int p = 0; p < 4; ++p)
                *(float4*)&sm.Bs[buf][bsk + 8 * p][bsc4] = bp[p];
        }
    };

    float acc[8][4] = {};
    load_tiles(0);
    store_tiles(0);
    __syncthreads();

    for (int t = 0; t < 16; ++t) {
        if (t < 15) load_tiles((t + 1) << 5);   // global prefetch under 1024 FMAs
        const int cur = t & 1;
        #pragma unroll
        for (int kk = 0; kk < 32; ++kk) {
            // As reads: 16 lanes same rg -> same addr broadcast; 4 rg's -> 4
            // distinct bank-quads. Bs reads: cg and cg+8 alias 2-way (free).
            float4 a0 = *(const float4*)&sm.As[cur][kk][rg << 3];
            float4 a1 = *(const float4*)&sm.As[cur][kk][(rg << 3) + 4];
            float4 bv = *(const float4*)&sm.Bs[cur][kk][cg << 2];
            float aa[8] = {a0.x, a0.y, a0.z, a0.w, a1.x, a1.y, a1.z, a1.w};
            float bb[4] = {bv.x, bv.y, bv.z, bv.w};
            #pragma unroll
            for (int i = 0; i < 8; ++i)
                #pragma unroll
                for (int j = 0; j < 4; ++j)
                    acc[i][j] += aa[i] * bb[j];
        }
        if (t < 15) {
            store_tiles(1 - cur);
            __syncthreads();
        }
    }

    float4 bv = make_float4(0.f, 0.f, 0.f, 0.f);
    if (bias) {
        float4 tb = *(const float4*)&bias[j0 + (cg << 2)];
        bv.x = bscale * tb.x; bv.y = bscale * tb.y;
        bv.z = bscale * tb.z; bv.w = bscale * tb.w;
    }
    #pragma unroll
    for (int r = 0; r < 8; ++r) {
        const int row = i0 + (rg << 3) + r;
        float4 o;
        o.x = acc[r][0] + bv.x; o.y = acc[r][1] + bv.y;
        o.z = acc[r][2] + bv.z; o.w = acc[r][3] + bv.w;
        *(float4*)&C[(size_t)row * HD + j0 + (cg << 2)] = o;
    }
}

// ---- pool: one block (128 thr) per tree; fully contiguous 128 KB sweep ----
// Thread t owns col4 t for all 64 rows: no reduction step needed.
__device__ __forceinline__
void pool_body(const float* __restrict__ x, float* __restrict__ P3, int tree) {
    const int tid = threadIdx.x;  // 0..127
    const float4* xp = (const float4*)x + (size_t)tree * 8192 + tid;
    float4 a0 = make_float4(0.f, 0.f, 0.f, 0.f), a1 = a0;
    #pragma unroll
    for (int g = 0; g < 8; ++g) {
        float4 v[8];
        #pragma unroll
        for (int i = 0; i < 8; ++i) v[i] = xp[(size_t)(g * 8 + i) * 128];
        #pragma unroll
        for (int i = 0; i < 8; i += 2) {
            a0.x += v[i].x;     a0.y += v[i].y;
            a0.z += v[i].z;     a0.w += v[i].w;
            a1.x += v[i + 1].x; a1.y += v[i + 1].y;
            a1.z += v[i + 1].z; a1.w += v[i + 1].w;
        }
    }
    a0.x += a1.x; a0.y += a1.y; a0.z += a1.z; a0.w += a1.w;
    ((float4*)P3)[tree * 128 + tid] = a0;
}

// ---- c0: one output per wave (2 per 128-thr block) ----
__device__ __forceinline__
void c0_body(const float* __restrict__ bz, const float* __restrict__ Wzf,
             const float* __restrict__ bzf, float* __restrict__ c0, int bb) {
    const int tid = threadIdx.x, lane = tid & 63, hb = lane << 3;
    const int j = bb * 2 + (tid >> 6);
    float4 s0 = *(const float4*)&bz[hb];
    float4 s1 = *(const float4*)&bz[hb + 4];
    #pragma unroll
    for (int q = 1; q < 4; ++q) {
        float4 t0 = *(const float4*)&bz[q * HD + hb];
        float4 t1 = *(const float4*)&bz[q * HD + hb + 4];
        s0.x += t0.x; s0.y += t0.y; s0.z += t0.z; s0.w += t0.w;
        s1.x += t1.x; s1.y += t1.y; s1.z += t1.z; s1.w += t1.w;
    }
    const float4* wr = (const float4*)&Wzf[(size_t)j * HD + hb];
    float4 w0 = wr[0], w1 = wr[1];
    float p = w0.x * s0.x + w0.y * s0.y + w0.z * s0.z + w0.w * s0.w
            + w1.x * s1.x + w1.y * s1.y + w1.z * s1.z + w1.w * s1.w;
    #pragma unroll
    for (int off = 32; off > 0; off >>= 1) p += __shfl_down(p, off);
    if (lane == 0) c0[j] = 4.f * (p + bzf[j]);
}

// ---- u: one output per wave (2 per block) ----
__device__ __forceinline__
void u_body(const float* __restrict__ M, const float* __restrict__ c0,
            float* __restrict__ u, int bb) {
    const int tid = threadIdx.x, lane = tid & 63, hb = lane << 3;
    const int j = bb * 2 + (tid >> 6);
    const float4* mr = (const float4*)&M[(size_t)j * HD + hb];
    const float4* cr = (const float4*)&c0[hb];
    float4 m0 = mr[0], m1 = mr[1], q0 = cr[0], q1 = cr[1];
    float p = m0.x * q0.x + m0.y * q0.y + m0.z * q0.z + m0.w * q0.w
            + m1.x * q1.x + m1.y * q1.y + m1.z * q1.z + m1.w * q1.w;
    #pragma unroll
    for (int off = 32; off > 0; off >>= 1) p += __shfl_down(p, off);
    if (lane == 0) u[j] = 4.f * p + c0[j];
}

// ---- D1: [0,64) M = Wzf@Wsum | [64,1088) pool | [1088,1344) c0 ----
__global__ __launch_bounds__(128) void kD1(
        const float* __restrict__ x, const float* __restrict__ Wz,
        const float* __restrict__ bz, const float* __restrict__ Wzf,
        const float* __restrict__ bzf,
        float* __restrict__ P3, float* __restrict__ M, float* __restrict__ c0) {
    __shared__ GemmSmem sm;
    const int b = blockIdx.x;
    if (b < 64) {
        gemm_tile<1>(Wzf, Wz, M, nullptr, 0.f, (b >> 3) << 6, (b & 7) << 6, sm);
    } else if (b < 1088) {
        pool_body(x, P3, b - 64);
    } else {
        c0_body(bz, Wzf, bzf, c0, b - 1088);
    }
}

// ---- D2: [0,128) Y1 = P3@M.T + 16c | [128,192) M2 = M@M | [192,448) u ----
__global__ __launch_bounds__(128) void kD2(
        const float* __restrict__ M, const float* __restrict__ P3,
        const float* __restrict__ c0,
        float* __restrict__ M2, float* __restrict__ Y1, float* __restrict__ u) {
    __shared__ GemmSmem sm;
    const int b = blockIdx.x;
    if (b < 128) {
        gemm_tile<2>(P3, M, Y1, c0, 16.f, (b >> 3) << 6, (b & 7) << 6, sm);
    } else if (b < 192) {
        const int bb = b - 128;
        gemm_tile<0>(M, M, M2, nullptr, 0.f, (bb >> 3) << 6, (bb & 7) << 6, sm);
    } else {
        u_body(M, c0, u, b - 192);
    }
}

// ---- D3: out = Y1 @ (M2).T + u ----
__global__ __launch_bounds__(128) void kD3(
        const float* __restrict__ Y1, const float* __restrict__ M2,
        const float* __restrict__ u, float* __restrict__ out) {
    __shared__ GemmSmem sm;
    const int b = blockIdx.x;
    gemm_tile<2>(Y1, M2, out, u, 1.f, (b >> 3) << 6, (b & 7) << 6, sm);
}

extern "C" void kernel_launch(void* const* d_in, const int* in_sizes, int n_in,
                              void* d_out, int out_size, void* d_ws, size_t ws_size,
                              hipStream_t stream) {
    const float* x   = (const float*)d_in[0];
    const float* Wz  = (const float*)d_in[1];
    const float* bz  = (const float*)d_in[2];
    const float* Wzf = (const float*)d_in[3];
    const float* bzf = (const float*)d_in[4];
    float* out = (float*)d_out;

    float* ws = (float*)d_ws;
    float* P3 = ws;                 // 1024*512
    float* Y1 = ws + 524288;        // 1024*512
    float* M  = ws + 1048576;       // 512*512
    float* M2 = ws + 1310720;       // 512*512
    float* c0 = ws + 1572864;       // 512
    float* u  = ws + 1573376;       // 512

    hipLaunchKernelGGL(kD1, dim3(1344), dim3(128), 0, stream,
                       x, Wz, bz, Wzf, bzf, P3, M, c0);
    hipLaunchKernelGGL(kD2, dim3(448), dim3(128), 0, stream,
                       M, P3, c0, M2, Y1, u);
    hipLaunchKernelGGL(kD3, dim3(128), dim3(128), 0, stream,
                       Y1, M2, u, out);
}